// Round 5
// baseline (163.433 us; speedup 1.0000x reference)
//
#include <hip/hip_runtime.h>

// PS_L20_LSTM — transposed-MFMA version: weights = A-operand, data = B-operand.
// Gate GEMM D = Wih·feat^T (K=15+bias col, zero-padded to 32) -> D reg-rows are
// 4 contiguous neurons -> packed b64 h-writes. Head GEMM D = W1·h^T -> B-frag is
// h in natural [row][neuron] layout (b128 reads). Gate bias folded into K=15 col.
// Wave-independent 32-row tiles, one staging barrier total.

typedef _Float16 half8v  __attribute__((ext_vector_type(8)));
typedef _Float16 half4v  __attribute__((ext_vector_type(4)));
typedef float    float4v __attribute__((ext_vector_type(4)));

#define N_SZ   2048
#define ROWS   262144
#define BLOCKT 256
#define NBLK   512          // 512 blocks x 4 waves x 4 iters x 32 rows = 262144
#define WITERS 4
#define WROWS  32

#define FS 24    // sFeat/sWihT row stride (f16): 48 B, 16B-aligned, 2-way banks
#define HS 136   // sW1T row stride (f16): 272 B, 16B-aligned, 2-way banks
#define SS 40    // sHs row stride (f16): 80 B, 16B-aligned, 2-way banks

__device__ __forceinline__ float fast_rcp(float x) { return __builtin_amdgcn_rcpf(x); }
__device__ __forceinline__ float sigm(float x)  { return fast_rcp(1.0f + __expf(-x)); }
__device__ __forceinline__ float tanh_f(float x){ return 1.0f - 2.0f * fast_rcp(1.0f + __expf(2.0f * x)); }
// |y| <= 1: odd deg-7 minimax, err ~1e-4, full-rate FMA pipe
__device__ __forceinline__ float tanh_c(float y) {
    const float t = y * y;
    return y * __builtin_fmaf(t, __builtin_fmaf(t, __builtin_fmaf(t,
            -0.02714f, 0.12052f), -0.33157f), 0.99986f);
}

__global__ __launch_bounds__(BLOCKT, 2)
void ps_lstm_t(const float* __restrict__ x_,
               const float* __restrict__ x1_,
               const float* __restrict__ x2_,
               const float* __restrict__ z1_,
               const float* __restrict__ z2_,
               const float* __restrict__ x1E_,
               const float* __restrict__ x2E_,
               const float* __restrict__ z1E_,
               const float* __restrict__ z2E_,
               const float* __restrict__ muB_,
               const float* __restrict__ lb_,
               const float* __restrict__ ub_,
               const float* __restrict__ Wih_,   // [512][15]
               const float* __restrict__ bih_,   // [512]
               const float* __restrict__ bhh_,   // [512]
               const float* __restrict__ W1_,    // [128][128]
               const float* __restrict__ b1_,    // [128]
               const float* __restrict__ W2_,    // [128]
               const float* __restrict__ b2_,    // [1]
               float* __restrict__ out_)         // [128][5*2048]
{
    __shared__ __align__(16) _Float16 sWihT[384 * FS];      // 18.4 KB: [gate*128+n][k], k15 = fused bias
    __shared__ __align__(16) _Float16 sW1T [128 * HS];      // 34.8 KB
    __shared__ __align__(16) _Float16 sFeat[4][WROWS * FS]; // 6 KB (per-wave)
    __shared__ __align__(16) _Float16 sHs  [4][WROWS * SS]; // 10.2 KB (per-wave 32-neuron slice)
    __shared__ __align__(16) float sB1[128];
    __shared__ __align__(16) float sW2[128];

    const int tid  = threadIdx.x;
    const int lane = tid & 63;
    const int w    = tid >> 6;
    const int c    = lane & 15;    // MFMA lane index (m for A, n for B/D-col)
    const int q    = lane >> 4;    // quad

    // ---------- one-time weight staging ----------
    for (int n3 = tid; n3 < 384; n3 += BLOCKT) {
        const int grow = n3 + (n3 >= 128 ? 128 : 0);  // skip dead f-gate
        #pragma unroll
        for (int k = 0; k < 15; ++k)
            sWihT[n3 * FS + k] = (_Float16)Wih_[grow * 15 + k];
        sWihT[n3 * FS + 15] = (_Float16)(bih_[grow] + bhh_[grow]);  // bias column
    }
    {
        const int n  = tid >> 1;
        const int hf = tid & 1;
        const float4* src = (const float4*)(W1_ + n * 128 + hf * 64);
        #pragma unroll
        for (int v = 0; v < 16; v += 2) {
            const float4 a  = src[v];
            const float4 bq = src[v + 1];
            half8v hh;
            hh[0] = (_Float16)a.x;  hh[1] = (_Float16)a.y;
            hh[2] = (_Float16)a.z;  hh[3] = (_Float16)a.w;
            hh[4] = (_Float16)bq.x; hh[5] = (_Float16)bq.y;
            hh[6] = (_Float16)bq.z; hh[7] = (_Float16)bq.w;
            *(half8v*)&sW1T[n * HS + hf * 64 + v * 4] = hh;
        }
    }
    for (int i = tid; i < 128; i += BLOCKT) { sB1[i] = b1_[i]; sW2[i] = W2_[i]; }
    const float b2v = b2_[0];

    __syncthreads();   // the only barrier

    const int gw = blockIdx.x * 4 + w;

    #pragma unroll 1
    for (int it = 0; it < WITERS; ++it) {
        const int rbase = (gw * WITERS + it) * WROWS;

        // ---------- stage 1: feature build (lanes 0..31, lane = row) ----------
        float ex = 0.f, ez1 = 0.f, ez2 = 0.f, eD1 = 0.f, eD2 = 0.f, elb = 0.f, eub = 0.f;
        if (lane < WROWS) {
            const int r = rbase + lane;
            const float x   = x_[r];
            const float x1  = x1_[r];
            const float x2  = x2_[r];
            float       z1  = z1_[r];
            float       z2  = z2_[r];
            const float x1E = x1E_[r];
            const float x2E = x2E_[r];
            const float z1E = z1E_[r];
            const float z2E = z2E_[r];
            const float mu  = muB_[r >> 11];

            z1 = ((z1 + mu) <= 0.0f) ? 0.0f : z1;
            z2 = ((z2 + mu) <= 0.0f) ? 0.0f : z2;
            float invD1 = (z1 + mu) * fast_rcp(x1 + mu + 1e-12f);
            float invD2 = (z2 + mu) * fast_rcp(x2 + mu + 1e-12f);
            invD1 = fminf(fmaxf(invD1, 0.0f), 100.0f);
            invD2 = fminf(fmaxf(invD2, 0.0f), 100.0f);

            const float f[15] = { x, x1, x2, z1, z2, x, z1, z2,
                                  x1E, x2E, z1E, z2E, mu, invD1, invD2 };
            half8v f0, f1;
            #pragma unroll
            for (int k = 0; k < 8; ++k) f0[k] = (_Float16)f[k];
            #pragma unroll
            for (int k = 0; k < 7; ++k) f1[k] = (_Float16)f[8 + k];
            f1[7] = (_Float16)1.0f;                    // bias activator (k=15)
            *(half8v*)&sFeat[w][lane * FS]     = f0;
            *(half8v*)&sFeat[w][lane * FS + 8] = f1;

            ex = x; ez1 = z1; ez2 = z2; eD1 = invD1; eD2 = invD2;
            elb = lb_[r]; eub = ub_[r];
        }

        // ---------- feat B-frags (loop-invariant): B[k=q*8+j][n=row c] ----------
        half8v z8;
        #pragma unroll
        for (int k = 0; k < 8; ++k) z8[k] = (_Float16)0.f;
        half8v fB[2];
        #pragma unroll
        for (int nt = 0; nt < 2; ++nt)
            fB[nt] = (q < 2) ? *(const half8v*)&sFeat[w][(nt * 16 + c) * FS + q * 8] : z8;

        float4v acc[8][2];
        #pragma unroll
        for (int mt = 0; mt < 8; ++mt)
            #pragma unroll
            for (int nt = 0; nt < 2; ++nt)
                acc[mt][nt] = (float4v){0.f, 0.f, 0.f, 0.f};

        #pragma unroll
        for (int kk = 0; kk < 4; ++kk) {
            // ----- gate GEMM + activations: produce h slice (neurons kk*32..kk*32+31) -----
            #pragma unroll
            for (int mtl = 0; mtl < 2; ++mtl) {
                const int mt = kk * 2 + mtl;
                // weight A-frags: A[m=neuron c][k=q*8+j]
                half8v Ai = z8, Ag = z8, Ao = z8;
                if (q < 2) {
                    const int nb = mt * 16 + c;
                    Ai = *(const half8v*)&sWihT[(      nb) * FS + q * 8];
                    Ag = *(const half8v*)&sWihT[(128 + nb) * FS + q * 8];
                    Ao = *(const half8v*)&sWihT[(256 + nb) * FS + q * 8];
                }
                #pragma unroll
                for (int nt = 0; nt < 2; ++nt) {
                    const float4v zc = {0.f, 0.f, 0.f, 0.f};
                    float4v di = __builtin_amdgcn_mfma_f32_16x16x32_f16(Ai, fB[nt], zc, 0, 0, 0);
                    float4v dg = __builtin_amdgcn_mfma_f32_16x16x32_f16(Ag, fB[nt], zc, 0, 0, 0);
                    float4v dv = __builtin_amdgcn_mfma_f32_16x16x32_f16(Ao, fB[nt], zc, 0, 0, 0);
                    // D: col c = row, reg-rows = neurons q*4+j (contiguous!) -> packed b64
                    half4v h4;
                    #pragma unroll
                    for (int j = 0; j < 4; ++j) {
                        const float cv = sigm(di[j]) * tanh_f(dg[j]);
                        h4[j] = (_Float16)(sigm(dv[j]) * tanh_c(cv));
                    }
                    *(half4v*)&sHs[w][(nt * 16 + c) * SS + mtl * 16 + q * 4] = h4;
                }
            }
            // ----- head GEMM k-step: B = h^T in natural [row][neuron] layout -----
            half8v hB[2];
            #pragma unroll
            for (int nt = 0; nt < 2; ++nt)
                hB[nt] = *(const half8v*)&sHs[w][(nt * 16 + c) * SS + q * 8];
            #pragma unroll
            for (int mt2 = 0; mt2 < 8; ++mt2) {
                const half8v A1 = *(const half8v*)&sW1T[(mt2 * 16 + c) * HS + kk * 32 + q * 8];
                #pragma unroll
                for (int nt = 0; nt < 2; ++nt)
                    acc[mt2][nt] = __builtin_amdgcn_mfma_f32_16x16x32_f16(A1, hB[nt], acc[mt2][nt], 0, 0, 0);
            }
        }

        // ---------- epilogue: relu(+b1)*W2, reduce over neurons -> p per row ----------
        float v0 = 0.f, v1 = 0.f;
        #pragma unroll
        for (int mt2 = 0; mt2 < 8; ++mt2) {
            // neurons mt2*16 + q*4 + j: broadcast float4 reads (uniform per quad)
            const float4 b1q = *(const float4*)&sB1[mt2 * 16 + q * 4];
            const float4 w2q = *(const float4*)&sW2[mt2 * 16 + q * 4];
            const float bb[4] = { b1q.x, b1q.y, b1q.z, b1q.w };
            const float ww[4] = { w2q.x, w2q.y, w2q.z, w2q.w };
            #pragma unroll
            for (int j = 0; j < 4; ++j) {
                v0 = __builtin_fmaf(fmaxf(acc[mt2][0][j] + bb[j], 0.f), ww[j], v0);
                v1 = __builtin_fmaf(fmaxf(acc[mt2][1][j] + bb[j], 0.f), ww[j], v1);
            }
        }
        // sum across quads (neuron dimension spans quads); col c = row stays
        v0 += __shfl_xor(v0, 16, 64);  v0 += __shfl_xor(v0, 32, 64);
        v1 += __shfl_xor(v1, 16, 64);  v1 += __shfl_xor(v1, 32, 64);

        if (lane < WROWS) {
            const int   r     = rbase + lane;
            const int   b     = r >> 11;
            const int   n     = r & (N_SZ - 1);
            const float p     = ((lane < 16) ? v0 : v1) + b2v;   // row = lane
            const float pxx   = fabsf(p) * ex;
            const float x_new = ex - pxx;
            float* ob = out_ + (size_t)b * (5 * N_SZ) + n;
            ob[0 * N_SZ] = x_new;
            ob[1 * N_SZ] = x_new - elb;               // has_lb all-true
            ob[2 * N_SZ] = eub - x_new;               // has_ub all-true
            ob[3 * N_SZ] = ez1 - eD1 * (ez1 - pxx);
            ob[4 * N_SZ] = ez2 - eD2 * (ez2 + pxx);
        }
    }
}

extern "C" void kernel_launch(void* const* d_in, const int* in_sizes, int n_in,
                              void* d_out, int out_size, void* d_ws, size_t ws_size,
                              hipStream_t stream) {
    (void)in_sizes; (void)n_in; (void)out_size; (void)d_ws; (void)ws_size;
    const float* x_   = (const float*)d_in[0];
    const float* x1_  = (const float*)d_in[1];
    const float* x2_  = (const float*)d_in[2];
    const float* z1_  = (const float*)d_in[3];
    const float* z2_  = (const float*)d_in[4];
    const float* x1E_ = (const float*)d_in[5];
    const float* x2E_ = (const float*)d_in[6];
    const float* z1E_ = (const float*)d_in[7];
    const float* z2E_ = (const float*)d_in[8];
    const float* muB_ = (const float*)d_in[9];
    const float* lb_  = (const float*)d_in[10];
    const float* ub_  = (const float*)d_in[11];
    const float* Wih_ = (const float*)d_in[14];
    const float* bih_ = (const float*)d_in[16];
    const float* bhh_ = (const float*)d_in[17];
    const float* W1_  = (const float*)d_in[18];
    const float* b1_  = (const float*)d_in[19];
    const float* W2_  = (const float*)d_in[20];
    const float* b2_  = (const float*)d_in[21];
    float* out_ = (float*)d_out;

    ps_lstm_t<<<NBLK, BLOCKT, 0, stream>>>(
        x_, x1_, x2_, z1_, z2_, x1E_, x2E_, z1E_, z2E_, muB_, lb_, ub_,
        Wih_, bih_, bhh_, W1_, b1_, W2_, b2_, out_);
}